// Round 3
// baseline (8492.755 us; speedup 1.0000x reference)
//
#include <hip/hip_runtime.h>

typedef unsigned short ushort_t;
typedef __bf16 bf16x8 __attribute__((ext_vector_type(8)));
typedef float f32x4 __attribute__((ext_vector_type(4)));

#define T_STEPS 512
#define BATCH 64
#define HDIM 1024
#define CHUNK 32                 // steps per gate-precompute chunk
#define NCHUNK (T_STEPS / CHUNK) // 16
#define MCH (CHUNK * BATCH)      // 2048 rows per chunk GEMM
// d_out (fp32): outs [512*64*1024] then h_T [65536] then c_T [65536]
#define OUTS_ELEMS 33554432ULL

__device__ __forceinline__ ushort_t f2bf(float f) {
    union { unsigned int i; float f; } v;
    v.f = f;
    unsigned int x = v.i;
    unsigned int r = (x + 0x7FFFu + ((x >> 16) & 1u)) >> 16;
    return (ushort_t)r;
}

__device__ __forceinline__ float bf2f(ushort_t u) {
    union { unsigned int i; float f; } v;
    v.i = ((unsigned int)u) << 16;
    return v.f;
}

struct Ptr8 { const float* p[8]; };
struct Ptr4 { const float* p[4]; };

// ---------------------------------------------------------------------------
// Transpose+convert 8 fp32 weight matrices [1024 k][1024 n] -> bf16 [1024 n][1024 k]
// ---------------------------------------------------------------------------
__global__ __launch_bounds__(256) void transpose8(Ptr8 in, ushort_t* __restrict__ out) {
    __shared__ ushort_t tile[64][65];
    int z = blockIdx.z;
    const float* src = in.p[z];
    ushort_t* dst = out + (size_t)z * 1024 * 1024;
    int bx = blockIdx.x * 64;  // n base
    int by = blockIdx.y * 64;  // k base
    int t = threadIdx.x;
#pragma unroll
    for (int i = 0; i < 16; i++) {
        int lin = t + i * 256;
        int r = lin >> 6, c = lin & 63;
        tile[r][c] = f2bf(src[(size_t)(by + r) * 1024 + bx + c]);
    }
    __syncthreads();
#pragma unroll
    for (int i = 0; i < 16; i++) {
        int lin = t + i * 256;
        int r = lin >> 6, c = lin & 63;
        dst[(size_t)(bx + r) * 1024 + by + c] = tile[c][r];
    }
}

// ---------------------------------------------------------------------------
// Chunk GEMM: G[m][n'] = A[m][:] @ wt_x[n'][:] + bias   (fp32 acc, bf16 out)
//   A: fp32 [2048 m][1024 k] (rows = 32 steps x 64 batch, contiguous slice)
//   wt_x: bf16 [4096 n'][1024 k], n' = g*1024 + n
// 128x128 tile, BK=32, 256 thr = 4 waves (2x2), each wave 64x64 (4x4 MFMA)
// ---------------------------------------------------------------------------
#define BK 32
#define LDK 40  // padded LDS row stride (80 B: 16B-aligned, 2-way conflicts = free)

__global__ __launch_bounds__(256) void chunk_gemm(
    const float* __restrict__ A,
    const ushort_t* __restrict__ Wt,
    Ptr4 biases,
    ushort_t* __restrict__ G)            // [2048 m][4096 n']
{
    __shared__ ushort_t As[128 * LDK];
    __shared__ ushort_t Bs[128 * LDK];

    int n0 = blockIdx.x * 128;   // never straddles a gate (1024 % 128 == 0)
    int m0 = blockIdx.y * 128;
    int t = threadIdx.x;
    int wave = t >> 6, lane = t & 63;
    int wm = (wave & 1) * 64, wn = (wave >> 1) * 64;
    int lrow = lane & 15, quad = lane >> 4;
    int lk = quad * 8;

    f32x4 acc[4][4] = {};

    for (int k0 = 0; k0 < 1024; k0 += BK) {
        __syncthreads();
        // A: fp32 load + convert. 128 rows x 32 k = 1024 float4 slots
#pragma unroll
        for (int i = 0; i < 4; i++) {
            int c = t + 256 * i;
            int r = c >> 3, kc = c & 7;           // 8 float4 per row
            const float4 v = *(const float4*)&A[(size_t)(m0 + r) * 1024 + k0 + kc * 4];
            ushort_t* d = &As[r * LDK + kc * 4];
            d[0] = f2bf(v.x); d[1] = f2bf(v.y); d[2] = f2bf(v.z); d[3] = f2bf(v.w);
        }
        // B: bf16 direct copy. 128 rows x 32 k = 512 bf16x8 slots
#pragma unroll
        for (int i = 0; i < 2; i++) {
            int c = t + 256 * i;
            int r = c >> 2, kc = c & 3;
            *(bf16x8*)&Bs[r * LDK + kc * 8] =
                *(const bf16x8*)&Wt[(size_t)(n0 + r) * 1024 + k0 + kc * 8];
        }
        __syncthreads();

        bf16x8 a[4], b[4];
#pragma unroll
        for (int i = 0; i < 4; i++)
            a[i] = *(const bf16x8*)&As[(wm + i * 16 + lrow) * LDK + lk];
#pragma unroll
        for (int j = 0; j < 4; j++)
            b[j] = *(const bf16x8*)&Bs[(wn + j * 16 + lrow) * LDK + lk];
#pragma unroll
        for (int i = 0; i < 4; i++)
#pragma unroll
            for (int j = 0; j < 4; j++)
                acc[i][j] = __builtin_amdgcn_mfma_f32_16x16x32_bf16(a[i], b[j], acc[i][j], 0, 0, 0);
    }

    int g = n0 >> 10;                       // uniform per block
    const float* bias = biases.p[g];
    int cg0 = (n0 & 1023) + wn;             // within-gate col base
#pragma unroll
    for (int j = 0; j < 4; j++) {
        int coln = n0 + wn + j * 16 + lrow;
        float bv = bias[cg0 + j * 16 + lrow];
#pragma unroll
        for (int i = 0; i < 4; i++) {
#pragma unroll
            for (int r = 0; r < 4; r++) {
                int rowm = m0 + wm + i * 16 + quad * 4 + r;
                G[(size_t)rowm * 4096 + coln] = f2bf(acc[i][j][r] + bv);
            }
        }
    }
}

// ---------------------------------------------------------------------------
// Init state from fp32 h0/c0
// ---------------------------------------------------------------------------
__global__ __launch_bounds__(256) void init_state(
    const float* __restrict__ h0, const float* __restrict__ c0,
    float* __restrict__ hf, float* __restrict__ cf, ushort_t* __restrict__ hb)
{
    int i = blockIdx.x * 256 + threadIdx.x;  // 65536
    float h = h0[i];
    hf[i] = h;
    cf[i] = c0[i];
    hb[i] = f2bf(h);
}

// ---------------------------------------------------------------------------
// One recurrent step. 128 WGs x 256 thr; WG wg owns hidden units [wg*8, wg*8+8).
// Virtual cols vc = g*8+u (32 per WG). Waves 2x2: wm=(w&1)*32 (batch),
// wn=(w>>1)*16 (vc). A (h bf16) and B (wt_h bf16) read direct from L2.
// ---------------------------------------------------------------------------
__global__ __launch_bounds__(256) void lstm_step(
    const ushort_t* __restrict__ WtH,   // bf16 [4][1024 n][1024 k]
    const ushort_t* __restrict__ Gc,    // bf16 chunk gates [2048 m][4096 n']
    const float* __restrict__ ret,      // fp32 [1024]
    float* __restrict__ cf,             // fp32 [64][1024] in/out (WG-private cols)
    const float* __restrict__ hf_in,
    float* __restrict__ hf_out,
    const ushort_t* __restrict__ hb_in, // bf16 h for GEMM
    ushort_t* __restrict__ hb_out,
    float* __restrict__ out,            // d_out (fp32)
    int t, int tc)
{
    __shared__ float S[64 * 32];  // S[b][vc]

    int wg = blockIdx.x;
    int u0 = wg * 8;
    int tid = threadIdx.x, wave = tid >> 6, lane = tid & 63;
    int wm = (wave & 1) * 32;
    int wn = (wave >> 1) * 16;
    int lrow = lane & 15, quad = lane >> 4;

    f32x4 acc0 = {}, acc1 = {};
    {
        int vc = wn + lrow;
        const ushort_t* bp = WtH + (size_t)(vc >> 3) * 1048576
                                 + (size_t)(u0 + (vc & 7)) * 1024 + quad * 8;
        const ushort_t* ap0 = hb_in + (size_t)(wm + lrow) * 1024 + quad * 8;
        const ushort_t* ap1 = ap0 + 16 * 1024;
#pragma unroll 4
        for (int k0 = 0; k0 < 1024; k0 += 32) {
            bf16x8 b  = *(const bf16x8*)(bp + k0);
            bf16x8 a0 = *(const bf16x8*)(ap0 + k0);
            bf16x8 a1 = *(const bf16x8*)(ap1 + k0);
            acc0 = __builtin_amdgcn_mfma_f32_16x16x32_bf16(a0, b, acc0, 0, 0, 0);
            acc1 = __builtin_amdgcn_mfma_f32_16x16x32_bf16(a1, b, acc1, 0, 0, 0);
        }
#pragma unroll
        for (int r = 0; r < 4; r++) {
            S[(wm + quad * 4 + r) * 32 + vc] = acc0[r];
            S[(wm + 16 + quad * 4 + r) * 32 + vc] = acc1[r];
        }
    }
    __syncthreads();

#pragma unroll
    for (int i = 0; i < 2; i++) {
        int lin = tid + i * 256;  // 0..511
        int b = lin >> 3, u = lin & 7;
        int hu = u0 + u;
        size_t gbase = ((size_t)tc * 64 + b) * 4096 + hu;
        float si = S[b * 32 + 0 + u]  + bf2f(Gc[gbase]);
        float sf = S[b * 32 + 8 + u]  + bf2f(Gc[gbase + 1024]);
        float so = S[b * 32 + 16 + u] + bf2f(Gc[gbase + 2048]);
        float sc = S[b * 32 + 24 + u] + bf2f(Gc[gbase + 3072]);
        float it = 1.f / (1.f + __expf(-si));
        float ft = 1.f / (1.f + __expf(-sf));
        float ot = 1.f / (1.f + __expf(-so));
        float gt = 1.f - 2.f / (__expf(2.f * sc) + 1.f);   // NaN-safe tanh
        int idx = b * 1024 + hu;
        float cn = cf[idx] * ft + it * gt;
        float tcn = 1.f - 2.f / (__expf(2.f * cn) + 1.f);  // NaN-safe tanh
        float hl = ot * tcn;
        float r = ret[hu];
        float hn = r * hf_in[idx] + (1.f - r) * hl;
        cf[idx] = cn;
        hf_out[idx] = hn;
        hb_out[idx] = f2bf(hn);
        out[(size_t)t * 65536 + idx] = hn;
    }
}

// ---------------------------------------------------------------------------
// Epilogue: append h_T and c_T (fp32) to d_out
// ---------------------------------------------------------------------------
__global__ __launch_bounds__(256) void epilogue_k(
    const float* __restrict__ hf_final, const float* __restrict__ cf,
    float* __restrict__ out)
{
    int i = blockIdx.x * 256 + threadIdx.x;  // 65536
    out[OUTS_ELEMS + i] = hf_final[i];
    out[OUTS_ELEMS + 65536 + i] = cf[i];
}

// ---------------------------------------------------------------------------
extern "C" void kernel_launch(void* const* d_in, const int* in_sizes, int n_in,
                              void* d_out, int out_size, void* d_ws, size_t ws_size,
                              hipStream_t stream)
{
    const float* input_ = (const float*)d_in[0];
    const float* h0   = (const float*)d_in[1];
    const float* c0   = (const float*)d_in[2];
    const float* w_xi = (const float*)d_in[3];
    const float* w_xf = (const float*)d_in[4];
    const float* w_xo = (const float*)d_in[5];
    const float* w_xc = (const float*)d_in[6];
    const float* w_hi = (const float*)d_in[7];
    const float* w_hf = (const float*)d_in[8];
    const float* w_ho = (const float*)d_in[9];
    const float* w_hc = (const float*)d_in[10];
    const float* b_i  = (const float*)d_in[11];
    const float* b_f  = (const float*)d_in[12];
    const float* b_o  = (const float*)d_in[13];
    const float* b_c  = (const float*)d_in[14];
    const float* ret  = (const float*)d_in[15];

    // workspace carve (total ~33 MiB)
    ushort_t* wt_x   = (ushort_t*)d_ws;            // 4*1M bf16  (8 MiB)
    ushort_t* wt_h   = wt_x + 4ULL * 1048576;      // 4*1M bf16  (8 MiB)
    ushort_t* gchunk = wt_h + 4ULL * 1048576;      // 2048*4096 bf16 (16 MiB)
    float*  cf  = (float*)(gchunk + (size_t)MCH * 4096);
    float*  hf0 = cf + 65536;
    float*  hf1 = hf0 + 65536;
    ushort_t* hb0 = (ushort_t*)(hf1 + 65536);
    ushort_t* hb1 = hb0 + 65536;
    float* out = (float*)d_out;

    Ptr8 p8; p8.p[0] = w_xi; p8.p[1] = w_xf; p8.p[2] = w_xo; p8.p[3] = w_xc;
             p8.p[4] = w_hi; p8.p[5] = w_hf; p8.p[6] = w_ho; p8.p[7] = w_hc;
    transpose8<<<dim3(16, 16, 8), 256, 0, stream>>>(p8, wt_x);

    init_state<<<256, 256, 0, stream>>>(h0, c0, hf0, cf, hb0);

    Ptr4 b4; b4.p[0] = b_i; b4.p[1] = b_f; b4.p[2] = b_o; b4.p[3] = b_c;

    for (int chunk = 0; chunk < NCHUNK; chunk++) {
        chunk_gemm<<<dim3(32, 16), 256, 0, stream>>>(
            input_ + (size_t)chunk * MCH * 1024, wt_x, b4, gchunk);
        for (int tc = 0; tc < CHUNK; tc++) {
            int t = chunk * CHUNK + tc;
            const ushort_t* hin = (t & 1) ? hb1 : hb0;
            ushort_t* hout      = (t & 1) ? hb0 : hb1;
            const float* hfin   = (t & 1) ? hf1 : hf0;
            float* hfout        = (t & 1) ? hf0 : hf1;
            lstm_step<<<128, 256, 0, stream>>>(wt_h, gchunk, ret, cf,
                                               hfin, hfout, hin, hout, out, t, tc);
        }
    }

    // t=511 is odd -> final h in hf0
    epilogue_k<<<256, 256, 0, stream>>>(hf0, cf, out);
}